// Round 13
// baseline (138.817 us; speedup 1.0000x reference)
//
#include <hip/hip_runtime.h>

constexpr int BN = 262144;
constexpr int H_ = 100;
constexpr int HHALF = 50;
constexpr int RS = 36; // packed weight-row stride in floats (144 B)

__device__ __forceinline__ float softplus_f(float x) {
    // |preact| <= ~6 for this data; direct form is safe for x < 88
    return __logf(1.0f + __expf(x));
}

// Pre-pass: pack weights into contiguous per-j rows in workspace:
// rows[j*36 + {0..7:W1m[j,:], 8..15:W1d[j,:], 16..23:W2m[:,j], 24..31:W2d[:,j], 32:b1m[j], 33:b1d[j]}]
// Contiguity lets the main kernel's uniform reads merge into wide s_loads.
__global__ __launch_bounds__(256) void pack_w(
    const float* __restrict__ W1m, const float* __restrict__ b1m,
    const float* __restrict__ W2m, const float* __restrict__ W1d,
    const float* __restrict__ b1d, const float* __restrict__ W2d,
    float* __restrict__ rows)
{
    const int gid = blockIdx.x * 256 + threadIdx.x;
    const int NT  = gridDim.x * 256;
    for (int idx = gid; idx < 800; idx += NT) {
        const int j = idx >> 3, k = idx & 7;      // W1* is [100][8] row-major
        rows[j * RS + 0 + k] = W1m[idx];
        rows[j * RS + 8 + k] = W1d[idx];
    }
    for (int idx = gid; idx < 800; idx += NT) {
        const int k = idx / 100, j = idx - k * 100; // W2* is [8][100] -> transpose
        rows[j * RS + 16 + k] = W2m[idx];
        rows[j * RS + 24 + k] = W2d[idx];
    }
    if (gid < H_) {
        rows[gid * RS + 32] = b1m[gid];
        rows[gid * RS + 33] = b1d[gid];
    }
}

__global__ __launch_bounds__(256) void sde_fused(
    const float* __restrict__ zt1, const float* __restrict__ zt2,
    const float* __restrict__ dtp, const float* __restrict__ b2m,
    const float* __restrict__ b2d, const float* __restrict__ rows,
    float* __restrict__ out)
{
    __shared__ float xch[256 * 9];   // partner-exchange, stride 9 -> 2-way alias (free)
    __shared__ float wsum[4];

    const int tid  = threadIdx.x;
    const int lane = tid & 63;
    const int wv   = tid >> 6;                  // 0..3
    const int pair = wv >> 1;                   // 0..1
    // half index MUST be wave-uniform in an SGPR so row reads stay s_load
    const int h    = __builtin_amdgcn_readfirstlane(wv & 1);
    const int row  = blockIdx.x * 128 + pair * 64 + lane;

    const float dt0  = dtp[0];
    const float sqdt = sqrtf(dt0);

    // zt1 row (2x float4, coalesced)
    float x[8];
    {
        const float4* p = reinterpret_cast<const float4*>(zt1) + (size_t)row * 2;
        float4 a = p[0], b = p[1];
        x[0]=a.x; x[1]=a.y; x[2]=a.z; x[3]=a.w;
        x[4]=b.x; x[5]=b.y; x[6]=b.z; x[7]=b.w;
    }
    // prefetch zt2 now; consumed after the loop (latency buried under compute)
    float4 z2a, z2b;
    {
        const float4* p = reinterpret_cast<const float4*>(zt2) + (size_t)row * 2;
        z2a = p[0]; z2b = p[1];
    }

    float am[8], ad[8];
    if (h == 0) {
        #pragma unroll
        for (int k = 0; k < 8; ++k) { am[k] = b2m[k]; ad[k] = b2d[k]; }
    } else {
        #pragma unroll
        for (int k = 0; k < 8; ++k) { am[k] = 0.f; ad[k] = 0.f; }
    }

    // each wave handles 50 of the 100 hidden units; ALL weight operands are
    // wave-uniform scalar-cache loads (contiguous rows -> wide s_load merges),
    // zero LDS traffic in the loop, FMAs take the weight as the SGPR operand.
    const float* __restrict__ rbase = rows + h * (HHALF * RS);
    #pragma unroll 2
    for (int jj = 0; jj < HHALF; ++jj) {
        const float* r = rbase + jj * RS;
        float pm = r[32], pd = r[33];
        #pragma unroll
        for (int k = 0; k < 8; ++k) {
            pm = fmaf(x[k], r[k],     pm);
            pd = fmaf(x[k], r[8 + k], pd);
        }
        const float hm = softplus_f(pm);
        const float hd = softplus_f(pd);
        #pragma unroll
        for (int k = 0; k < 8; ++k) {
            am[k] = fmaf(hm, r[16 + k], am[k]);
            ad[k] = fmaf(hd, r[24 + k], ad[k]);
        }
    }

    // exchange partials with partner wave (tid ^ 64)
    float* mine = &xch[tid * 9];
    if (h == 0) {   // I finish k=0..3; ship k=4..7 to partner
        mine[0]=am[4]; mine[1]=am[5]; mine[2]=am[6]; mine[3]=am[7];
        mine[4]=ad[4]; mine[5]=ad[5]; mine[6]=ad[6]; mine[7]=ad[7];
    } else {        // I finish k=4..7; ship k=0..3
        mine[0]=am[0]; mine[1]=am[1]; mine[2]=am[2]; mine[3]=am[3];
        mine[4]=ad[0]; mine[5]=ad[1]; mine[6]=ad[2]; mine[7]=ad[3];
    }
    __syncthreads();
    const float* part = &xch[(tid ^ 64) * 9];

    float* __restrict__ mu_out = out + 1;
    float* __restrict__ sg_out = out + 1 + (size_t)BN * 8;

    float t1 = 0.f, t2 = 0.f, t3 = 0.f, t4 = 0.f;

    // epilogue for my 4 output columns; all register indices static (no scratch)
#define EPI(K0, ZB)                                                          \
    {                                                                        \
        const float z2v[4] = {ZB.x, ZB.y, ZB.z, ZB.w};                       \
        _Pragma("unroll")                                                    \
        for (int q = 0; q < 4; ++q) {                                        \
            const int k = K0 + q;                                            \
            const float a_m = am[k] + part[q];                               \
            const float a_d = ad[k] + part[4 + q];                           \
            const float mu = a_m * dt0;                                      \
            const float y  = a_d;              /* log(D) exactly */          \
            const float Dk = __expf(y);                                      \
            const float iv = __expf(-2.0f * y); /* 1/D^2 */                  \
            const float dz = z2v[q] - x[k];                                  \
            t1 += y;                                                         \
            t2 = fmaf(dz * dz, iv, t2);                                      \
            t3 = fmaf(dz * mu, iv, t3);                                      \
            t4 = fmaf(mu * mu, iv, t4);                                      \
            mu_out[(size_t)row * 8 + k] = mu;                                \
            sg_out[(size_t)row * 8 + k] = Dk * sqdt;                         \
        }                                                                    \
    }

    if (h == 0) { EPI(0, z2a) } else { EPI(4, z2b) }
#undef EPI

    // per-thread share: 0.5*const + 0.5*(2 t1 + t2 - 2 t3 + t4) over my 4 k's
    float nll = fmaf(0.5f, (2.0f * t1 + t2 - 2.0f * t3 + t4),
                     3.67575413281869039f); // 0.5 * (DIM/2 * log(2*pi))

    #pragma unroll
    for (int off = 32; off > 0; off >>= 1) nll += __shfl_down(nll, off);

    if (lane == 0) wsum[wv] = nll;
    __syncthreads();
    if (tid == 0) atomicAdd(out, wsum[0] + wsum[1] + wsum[2] + wsum[3]);
}

extern "C" void kernel_launch(void* const* d_in, const int* in_sizes, int n_in,
                              void* d_out, int out_size, void* d_ws, size_t ws_size,
                              hipStream_t stream) {
    float* rows = (float*)d_ws;   // 100*36*4 = 14.4 KB of scratch
    hipMemsetAsync(d_out, 0, sizeof(float), stream);
    pack_w<<<4, 256, 0, stream>>>(
        (const float*)d_in[3], (const float*)d_in[4],   // W1m, b1m
        (const float*)d_in[5],                          // W2m
        (const float*)d_in[7], (const float*)d_in[8],   // W1d, b1d
        (const float*)d_in[9],                          // W2d
        rows);
    sde_fused<<<BN / 128, 256, 0, stream>>>(
        (const float*)d_in[0], (const float*)d_in[1], (const float*)d_in[2],
        (const float*)d_in[6], (const float*)d_in[10],  // b2m, b2d
        rows, (float*)d_out);
}

// Round 14
// 135.342 us; speedup vs baseline: 1.0257x; 1.0257x over previous
//
#include <hip/hip_runtime.h>

constexpr int BN = 262144;
constexpr int H_ = 100;
constexpr int HHALF = 50;
constexpr int RS = 36; // packed weight-row stride in floats (144 B)

typedef float v2f __attribute__((ext_vector_type(2)));

// Pre-pass: pack weights into contiguous per-j rows in workspace, with
// softplus base-2 constants folded in:
//   W1',b1' scaled by log2(e)  ->  p' = log2e*(W1 x + b1), 2^p' = e^p
//   W2' scaled by ln(2)        ->  W2' * log2(1+2^p') == W2 * softplus(p)
// rows[j*36 + {0..7:W1m', 8..15:W1d', 16..23:W2m'^T, 24..31:W2d'^T, 32:b1m', 33:b1d'}]
__global__ __launch_bounds__(256) void pack_w(
    const float* __restrict__ W1m, const float* __restrict__ b1m,
    const float* __restrict__ W2m, const float* __restrict__ W1d,
    const float* __restrict__ b1d, const float* __restrict__ W2d,
    float* __restrict__ rows)
{
    constexpr float LOG2E = 1.4426950408889634f;
    constexpr float LN2   = 0.6931471805599453f;
    const int gid = blockIdx.x * 256 + threadIdx.x;
    const int NT  = gridDim.x * 256;
    for (int idx = gid; idx < 800; idx += NT) {
        const int j = idx >> 3, k = idx & 7;        // W1* is [100][8] row-major
        rows[j * RS + 0 + k] = W1m[idx] * LOG2E;
        rows[j * RS + 8 + k] = W1d[idx] * LOG2E;
    }
    for (int idx = gid; idx < 800; idx += NT) {
        const int k = idx / 100, j = idx - k * 100; // W2* is [8][100] -> transpose
        rows[j * RS + 16 + k] = W2m[idx] * LN2;
        rows[j * RS + 24 + k] = W2d[idx] * LN2;
    }
    if (gid < H_) {
        rows[gid * RS + 32] = b1m[gid] * LOG2E;
        rows[gid * RS + 33] = b1d[gid] * LOG2E;
    }
}

__global__ __launch_bounds__(256) void sde_fused(
    const float* __restrict__ zt1, const float* __restrict__ zt2,
    const float* __restrict__ dtp, const float* __restrict__ b2m,
    const float* __restrict__ b2d, const float* __restrict__ rows,
    float* __restrict__ out)
{
    __shared__ float xch[256 * 9];   // partner-exchange, stride 9 -> 2-way alias (free)
    __shared__ float wsum[4];

    const int tid  = threadIdx.x;
    const int lane = tid & 63;
    const int wv   = tid >> 6;                  // 0..3
    const int pair = wv >> 1;                   // 0..1
    // half index MUST be wave-uniform in an SGPR so row reads stay s_load
    const int h    = __builtin_amdgcn_readfirstlane(wv & 1);
    const int row  = blockIdx.x * 128 + pair * 64 + lane;

    const float dt0  = dtp[0];
    const float sqdt = sqrtf(dt0);

    // zt1 row (2x float4, coalesced) packed into 4x float2 lanes
    v2f xv[4];
    float x[8];
    {
        const float4* p = reinterpret_cast<const float4*>(zt1) + (size_t)row * 2;
        float4 a = p[0], b = p[1];
        x[0]=a.x; x[1]=a.y; x[2]=a.z; x[3]=a.w;
        x[4]=b.x; x[5]=b.y; x[6]=b.z; x[7]=b.w;
        xv[0] = (v2f){a.x, a.y}; xv[1] = (v2f){a.z, a.w};
        xv[2] = (v2f){b.x, b.y}; xv[3] = (v2f){b.z, b.w};
    }
    // prefetch zt2 now; consumed after the loop (latency buried under compute)
    float4 z2a, z2b;
    {
        const float4* p = reinterpret_cast<const float4*>(zt2) + (size_t)row * 2;
        z2a = p[0]; z2b = p[1];
    }

    v2f amv[4], adv[4];
    if (h == 0) {
        #pragma unroll
        for (int q = 0; q < 4; ++q) {
            amv[q] = (v2f){b2m[2*q], b2m[2*q+1]};
            adv[q] = (v2f){b2d[2*q], b2d[2*q+1]};
        }
    } else {
        #pragma unroll
        for (int q = 0; q < 4; ++q) { amv[q] = (v2f){0.f, 0.f}; adv[q] = (v2f){0.f, 0.f}; }
    }

    // each wave handles 50 of the 100 hidden units. Weights arrive as wide
    // wave-uniform s_loads; FMAs are packed (v_pk_fma_f32, 2 MACs/instr);
    // softplus is base-2 (constants folded into weights): 3 instrs, 2 trans.
    const float* __restrict__ rbase = rows + h * (HHALF * RS);
    #pragma unroll 2
    for (int jj = 0; jj < HHALF; ++jj) {
        const float* r = rbase + jj * RS;
        const v2f* rv = reinterpret_cast<const v2f*>(r);
        v2f pmv = (v2f){0.f, 0.f}, pdv = (v2f){0.f, 0.f};
        #pragma unroll
        for (int q = 0; q < 4; ++q) {
            pmv = __builtin_elementwise_fma(xv[q], rv[q],     pmv);
            pdv = __builtin_elementwise_fma(xv[q], rv[4 + q], pdv);
        }
        const float pm = (pmv.x + pmv.y) + r[32];
        const float pd = (pdv.x + pdv.y) + r[33];
        const float hm = log2f(1.0f + exp2f(pm));   // v_exp + v_add + v_log
        const float hd = log2f(1.0f + exp2f(pd));
        const v2f hm2 = (v2f){hm, hm};
        const v2f hd2 = (v2f){hd, hd};
        #pragma unroll
        for (int q = 0; q < 4; ++q) {
            amv[q] = __builtin_elementwise_fma(hm2, rv[8 + q],  amv[q]);
            adv[q] = __builtin_elementwise_fma(hd2, rv[12 + q], adv[q]);
        }
    }

    // exchange partials with partner wave (tid ^ 64)
    float* mine = &xch[tid * 9];
    if (h == 0) {   // I finish k=0..3; ship k=4..7 to partner
        mine[0]=amv[2].x; mine[1]=amv[2].y; mine[2]=amv[3].x; mine[3]=amv[3].y;
        mine[4]=adv[2].x; mine[5]=adv[2].y; mine[6]=adv[3].x; mine[7]=adv[3].y;
    } else {        // I finish k=4..7; ship k=0..3
        mine[0]=amv[0].x; mine[1]=amv[0].y; mine[2]=amv[1].x; mine[3]=amv[1].y;
        mine[4]=adv[0].x; mine[5]=adv[0].y; mine[6]=adv[1].x; mine[7]=adv[1].y;
    }
    __syncthreads();
    const float* part = &xch[(tid ^ 64) * 9];

    float* __restrict__ mu_out = out + 1;
    float* __restrict__ sg_out = out + 1 + (size_t)BN * 8;

    float t1 = 0.f, t2 = 0.f, t3 = 0.f, t4 = 0.f;

    // epilogue for my 4 output columns; all register indices static (no scratch)
#define EPI(K0, A0, A1, D0, D1, ZB)                                          \
    {                                                                        \
        const float amk[4] = {A0.x, A0.y, A1.x, A1.y};                       \
        const float adk[4] = {D0.x, D0.y, D1.x, D1.y};                       \
        const float z2v[4] = {ZB.x, ZB.y, ZB.z, ZB.w};                       \
        _Pragma("unroll")                                                    \
        for (int q = 0; q < 4; ++q) {                                        \
            const int k = K0 + q;                                            \
            const float a_m = amk[q] + part[q];                              \
            const float a_d = adk[q] + part[4 + q];                          \
            const float mu = a_m * dt0;                                      \
            const float y  = a_d;              /* log(D) exactly */          \
            const float Dk = __expf(y);                                      \
            const float iv = __expf(-2.0f * y); /* 1/D^2 */                  \
            const float dz = z2v[q] - x[k];                                  \
            t1 += y;                                                         \
            t2 = fmaf(dz * dz, iv, t2);                                      \
            t3 = fmaf(dz * mu, iv, t3);                                      \
            t4 = fmaf(mu * mu, iv, t4);                                      \
            mu_out[(size_t)row * 8 + k] = mu;                                \
            sg_out[(size_t)row * 8 + k] = Dk * sqdt;                         \
        }                                                                    \
    }

    if (h == 0) { EPI(0, amv[0], amv[1], adv[0], adv[1], z2a) }
    else        { EPI(4, amv[2], amv[3], adv[2], adv[3], z2b) }
#undef EPI

    // per-thread share: 0.5*const + 0.5*(2 t1 + t2 - 2 t3 + t4) over my 4 k's
    float nll = fmaf(0.5f, (2.0f * t1 + t2 - 2.0f * t3 + t4),
                     3.67575413281869039f); // 0.5 * (DIM/2 * log(2*pi))

    #pragma unroll
    for (int off = 32; off > 0; off >>= 1) nll += __shfl_down(nll, off);

    if (lane == 0) wsum[wv] = nll;
    __syncthreads();
    if (tid == 0) atomicAdd(out, wsum[0] + wsum[1] + wsum[2] + wsum[3]);
}

extern "C" void kernel_launch(void* const* d_in, const int* in_sizes, int n_in,
                              void* d_out, int out_size, void* d_ws, size_t ws_size,
                              hipStream_t stream) {
    float* rows = (float*)d_ws;   // 100*36*4 = 14.4 KB of scratch
    hipMemsetAsync(d_out, 0, sizeof(float), stream);
    pack_w<<<4, 256, 0, stream>>>(
        (const float*)d_in[3], (const float*)d_in[4],   // W1m, b1m
        (const float*)d_in[5],                          // W2m
        (const float*)d_in[7], (const float*)d_in[8],   // W1d, b1d
        (const float*)d_in[9],                          // W2d
        rows);
    sde_fused<<<BN / 128, 256, 0, stream>>>(
        (const float*)d_in[0], (const float*)d_in[1], (const float*)d_in[2],
        (const float*)d_in[6], (const float*)d_in[10],  // b2m, b2d
        rows, (float*)d_out);
}

// Round 18
// 129.639 us; speedup vs baseline: 1.0708x; 1.0440x over previous
//
#include <hip/hip_runtime.h>

constexpr int BN = 262144;
constexpr int H_ = 100;
constexpr int HHALF = 50;
constexpr int RS = 36; // packed weight-row stride in floats (144 B)

typedef float v2f __attribute__((ext_vector_type(2)));

// Pre-pass: pack weights into contiguous per-j rows, softplus base-2 folded:
//   W1',b1' scaled by log2(e); W2' scaled by ln(2)
//   => W2' * log2(1 + 2^(W1'x+b1')) == W2 * softplus(W1 x + b1)
__global__ __launch_bounds__(256) void pack_w(
    const float* __restrict__ W1m, const float* __restrict__ b1m,
    const float* __restrict__ W2m, const float* __restrict__ W1d,
    const float* __restrict__ b1d, const float* __restrict__ W2d,
    float* __restrict__ rows)
{
    constexpr float LOG2E = 1.4426950408889634f;
    constexpr float LN2   = 0.6931471805599453f;
    const int gid = blockIdx.x * 256 + threadIdx.x;
    const int NT  = gridDim.x * 256;
    for (int idx = gid; idx < 800; idx += NT) {
        const int j = idx >> 3, k = idx & 7;        // W1* is [100][8] row-major
        rows[j * RS + 0 + k] = W1m[idx] * LOG2E;
        rows[j * RS + 8 + k] = W1d[idx] * LOG2E;
    }
    for (int idx = gid; idx < 800; idx += NT) {
        const int k = idx / 100, j = idx - k * 100; // W2* is [8][100] -> transpose
        rows[j * RS + 16 + k] = W2m[idx] * LN2;
        rows[j * RS + 24 + k] = W2d[idx] * LN2;
    }
    if (gid < H_) {
        rows[gid * RS + 32] = b1m[gid] * LOG2E;
        rows[gid * RS + 33] = b1d[gid] * LOG2E;
    }
}

__global__ __launch_bounds__(256) void sde_fused(
    const float* __restrict__ zt1, const float* __restrict__ zt2,
    const float* __restrict__ dtp, const float* __restrict__ b2m,
    const float* __restrict__ b2d, const float* __restrict__ rows,
    float* __restrict__ out)
{
    __shared__ float xch[256 * 17];  // 2-row partner exchange; odd stride -> 2-way alias (free)
    __shared__ float wsum[4];

    const int tid  = threadIdx.x;
    const int lane = tid & 63;
    const int wv   = tid >> 6;                  // 0..3
    const int pair = wv >> 1;                   // 0..1
    // half index MUST be wave-uniform in an SGPR so row reads stay s_load
    const int h    = __builtin_amdgcn_readfirstlane(wv & 1);
    const int rowA = blockIdx.x * 256 + pair * 128 + lane;
    const int rowB = rowA + 64;

    const float dt0  = dtp[0];
    const float sqdt = sqrtf(dt0);

    // two zt1 rows per thread (ILP: two independent dependency chains per iter)
    v2f xA[4], xB[4];
    {
        const float4* p = reinterpret_cast<const float4*>(zt1);
        float4 a0 = p[(size_t)rowA * 2], a1 = p[(size_t)rowA * 2 + 1];
        float4 b0 = p[(size_t)rowB * 2], b1 = p[(size_t)rowB * 2 + 1];
        xA[0]=(v2f){a0.x,a0.y}; xA[1]=(v2f){a0.z,a0.w};
        xA[2]=(v2f){a1.x,a1.y}; xA[3]=(v2f){a1.z,a1.w};
        xB[0]=(v2f){b0.x,b0.y}; xB[1]=(v2f){b0.z,b0.w};
        xB[2]=(v2f){b1.x,b1.y}; xB[3]=(v2f){b1.z,b1.w};
    }

    v2f amA[4], adA[4], amB[4], adB[4];
    if (h == 0) {
        #pragma unroll
        for (int q = 0; q < 4; ++q) {
            const v2f bm = (v2f){b2m[2*q], b2m[2*q+1]};
            const v2f bd = (v2f){b2d[2*q], b2d[2*q+1]};
            amA[q] = bm; adA[q] = bd; amB[q] = bm; adB[q] = bd;
        }
    } else {
        #pragma unroll
        for (int q = 0; q < 4; ++q) {
            amA[q] = (v2f){0.f,0.f}; adA[q] = (v2f){0.f,0.f};
            amB[q] = (v2f){0.f,0.f}; adB[q] = (v2f){0.f,0.f};
        }
    }

    // each wave handles 50 of the 100 hidden units for BOTH rows; weights are
    // wave-uniform wide s_loads; FMAs packed; softplus base-2 (3 instr each).
    const float* __restrict__ rbase = rows + h * (HHALF * RS);
    #pragma unroll 2
    for (int jj = 0; jj < HHALF; ++jj) {
        const float* r = rbase + jj * RS;
        const v2f* rv = reinterpret_cast<const v2f*>(r);
        v2f pmA=(v2f){0.f,0.f}, pdA=(v2f){0.f,0.f};
        v2f pmB=(v2f){0.f,0.f}, pdB=(v2f){0.f,0.f};
        #pragma unroll
        for (int q = 0; q < 4; ++q) {
            pmA = __builtin_elementwise_fma(xA[q], rv[q],     pmA);
            pmB = __builtin_elementwise_fma(xB[q], rv[q],     pmB);
            pdA = __builtin_elementwise_fma(xA[q], rv[4 + q], pdA);
            pdB = __builtin_elementwise_fma(xB[q], rv[4 + q], pdB);
        }
        const float pA = (pmA.x + pmA.y) + r[32];
        const float qA = (pdA.x + pdA.y) + r[33];
        const float pB = (pmB.x + pmB.y) + r[32];
        const float qB = (pdB.x + pdB.y) + r[33];
        const float hmA = log2f(1.0f + exp2f(pA));   // 4 independent trans chains
        const float hdA = log2f(1.0f + exp2f(qA));
        const float hmB = log2f(1.0f + exp2f(pB));
        const float hdB = log2f(1.0f + exp2f(qB));
        const v2f hmA2=(v2f){hmA,hmA}, hdA2=(v2f){hdA,hdA};
        const v2f hmB2=(v2f){hmB,hmB}, hdB2=(v2f){hdB,hdB};
        #pragma unroll
        for (int q = 0; q < 4; ++q) {
            amA[q] = __builtin_elementwise_fma(hmA2, rv[8 + q],  amA[q]);
            amB[q] = __builtin_elementwise_fma(hmB2, rv[8 + q],  amB[q]);
            adA[q] = __builtin_elementwise_fma(hdA2, rv[12 + q], adA[q]);
            adB[q] = __builtin_elementwise_fma(hdB2, rv[12 + q], adB[q]);
        }
    }

    // issue zt2 loads NOW (my half only: h selects float4); latency hides
    // under the LDS exchange + barrier below
    const float4* z2p = reinterpret_cast<const float4*>(zt2);
    const float4 zA = z2p[(size_t)rowA * 2 + h];
    const float4 zB = z2p[(size_t)rowB * 2 + h];

    // exchange partials with partner wave (tid ^ 64): 16 floats (2 rows x 4 m + 4 d)
    float* mine = &xch[tid * 17];
    if (h == 0) {   // I finish k=0..3; ship k=4..7
        mine[0]=amA[2].x; mine[1]=amA[2].y; mine[2]=amA[3].x; mine[3]=amA[3].y;
        mine[4]=adA[2].x; mine[5]=adA[2].y; mine[6]=adA[3].x; mine[7]=adA[3].y;
        mine[8]=amB[2].x; mine[9]=amB[2].y; mine[10]=amB[3].x; mine[11]=amB[3].y;
        mine[12]=adB[2].x; mine[13]=adB[2].y; mine[14]=adB[3].x; mine[15]=adB[3].y;
    } else {        // I finish k=4..7; ship k=0..3
        mine[0]=amA[0].x; mine[1]=amA[0].y; mine[2]=amA[1].x; mine[3]=amA[1].y;
        mine[4]=adA[0].x; mine[5]=adA[0].y; mine[6]=adA[1].x; mine[7]=adA[1].y;
        mine[8]=amB[0].x; mine[9]=amB[0].y; mine[10]=amB[1].x; mine[11]=amB[1].y;
        mine[12]=adB[0].x; mine[13]=adB[0].y; mine[14]=adB[1].x; mine[15]=adB[1].y;
    }
    __syncthreads();
    const float* part = &xch[(tid ^ 64) * 17];

    float* __restrict__ mu_out = out + 1;
    float* __restrict__ sg_out = out + 1 + (size_t)BN * 8;

    float t1 = 0.f, t2 = 0.f, t3 = 0.f, t4 = 0.f;

    // epilogue: my 4 output columns for each of my 2 rows; static reg indices
#define EPI(K0, A0, A1, D0, D1, X0, X1, Z, PB, ROW)                          \
    {                                                                        \
        const float amk[4] = {A0.x, A0.y, A1.x, A1.y};                       \
        const float adk[4] = {D0.x, D0.y, D1.x, D1.y};                       \
        const float xk[4]  = {X0.x, X0.y, X1.x, X1.y};                       \
        const float z2v[4] = {Z.x, Z.y, Z.z, Z.w};                           \
        _Pragma("unroll")                                                    \
        for (int q = 0; q < 4; ++q) {                                        \
            const int k = K0 + q;                                            \
            const float a_m = amk[q] + part[PB + q];                         \
            const float a_d = adk[q] + part[PB + 4 + q];                     \
            const float mu = a_m * dt0;                                      \
            const float y  = a_d;              /* log(D) exactly */          \
            const float Dk = __expf(y);                                      \
            const float iv = __expf(-2.0f * y); /* 1/D^2 */                  \
            const float dz = z2v[q] - xk[q];                                 \
            t1 += y;                                                         \
            t2 = fmaf(dz * dz, iv, t2);                                      \
            t3 = fmaf(dz * mu, iv, t3);                                      \
            t4 = fmaf(mu * mu, iv, t4);                                      \
            mu_out[(size_t)(ROW) * 8 + k] = mu;                              \
            sg_out[(size_t)(ROW) * 8 + k] = Dk * sqdt;                       \
        }                                                                    \
    }

    if (h == 0) {
        EPI(0, amA[0], amA[1], adA[0], adA[1], xA[0], xA[1], zA, 0, rowA)
        EPI(0, amB[0], amB[1], adB[0], adB[1], xB[0], xB[1], zB, 8, rowB)
    } else {
        EPI(4, amA[2], amA[3], adA[2], adA[3], xA[2], xA[3], zA, 0, rowA)
        EPI(4, amB[2], amB[3], adB[2], adB[3], xB[2], xB[3], zB, 8, rowB)
    }
#undef EPI

    // per-thread share covers 2 rows x 4 k's: 2 x 0.5*const + 0.5*(...)
    float nll = fmaf(0.5f, (2.0f * t1 + t2 - 2.0f * t3 + t4),
                     7.3515082656373808f); // 2 * 0.5 * (DIM/2 * log(2*pi))

    #pragma unroll
    for (int off = 32; off > 0; off >>= 1) nll += __shfl_down(nll, off);

    if (lane == 0) wsum[wv] = nll;
    __syncthreads();
    if (tid == 0) atomicAdd(out, wsum[0] + wsum[1] + wsum[2] + wsum[3]);
}

extern "C" void kernel_launch(void* const* d_in, const int* in_sizes, int n_in,
                              void* d_out, int out_size, void* d_ws, size_t ws_size,
                              hipStream_t stream) {
    float* rows = (float*)d_ws;   // 100*36*4 = 14.4 KB of scratch
    hipMemsetAsync(d_out, 0, sizeof(float), stream);
    pack_w<<<4, 256, 0, stream>>>(
        (const float*)d_in[3], (const float*)d_in[4],   // W1m, b1m
        (const float*)d_in[5],                          // W2m
        (const float*)d_in[7], (const float*)d_in[8],   // W1d, b1d
        (const float*)d_in[9],                          // W2d
        rows);
    sde_fused<<<BN / 256, 256, 0, stream>>>(
        (const float*)d_in[0], (const float*)d_in[1], (const float*)d_in[2],
        (const float*)d_in[6], (const float*)d_in[10],  // b2m, b2d
        rows, (float*)d_out);
}